// Round 1
// baseline (319.684 us; speedup 1.0000x reference)
//
#include <hip/hip_runtime.h>
#include <hip/hip_bf16.h>
#include <math.h>

#define SS 200
#define BB 1024
#define DD 128
#define FF 512
#define LL1 80
#define LL2 40
#define PP (SS*BB)
#define MASK_FILL_F (-4294967295.0f)
#define NTILE 13            // 13 s-tiles of 16 rows = 208 (200 live)

typedef short bf16x8 __attribute__((ext_vector_type(8)));
typedef float f32x4  __attribute__((ext_vector_type(4)));

static __device__ __forceinline__ unsigned short f2bf(float x) {
    __hip_bfloat16 h = __float2bfloat16(x);
    return *reinterpret_cast<unsigned short*>(&h);
}
static __device__ __forceinline__ float bf2f(unsigned short u) {
    __hip_bfloat16 h = *reinterpret_cast<__hip_bfloat16*>(&u);
    return __bfloat162float(h);
}
// truncation split: hi = top 16 bits, lo = bf16(x - hi). |err| ~ 2^-16 rel.
static __device__ __forceinline__ void split8(const float* x, bf16x8& ah, bf16x8& al) {
#pragma unroll
    for (int j = 0; j < 8; ++j) {
        unsigned u = __float_as_uint(x[j]);
        ah[j] = (short)(u >> 16);
        float hi = __uint_as_float(u & 0xffff0000u);
        al[j] = (short)f2bf(x[j] - hi);
    }
}

// ---------------------------------------------------------------------------
// Merged prep (unchanged math). blocks 0-29: W1 fold+split -> bfr1 phase-major:
//   fid = ((h*6 + step)*2 + hl)*5 + nt, step = ktL*3+seg, kt = h*2+ktL
// blocks 30-34: W2 pad+split -> bfr2, fid2 = (kt*3+nt)*2+hl.
// block 35: mask layout detect.
__global__ void k_prep_all(const float* __restrict__ W1, const float* __restrict__ W2,
                           const unsigned char* __restrict__ mask,
                           unsigned short* __restrict__ bfr1,
                           unsigned short* __restrict__ bfr2, int* __restrict__ flag) {
    const int blk = blockIdx.x;
    if (blk == 35) {
        if (threadIdx.x == 0) {
            int f = 0;
            for (int i = 0; i < 256; ++i)
                if ((i & 3) && mask[i]) f = 1;
            *flag = f;
        }
        return;
    }
    if (blk < 30) {
        int t = blk * 256 + threadIdx.x;
        if (t >= 120 * 64) return;
        int lane = t & 63;
        int fid  = t >> 6;
        int nt   = fid % 5;
        int hl   = (fid / 5) % 2;
        int step = (fid / 10) % 6;
        int h    = fid / 60;
        int ktL  = step / 3;
        int seg  = step - 3 * ktL;
        int kt   = h * 2 + ktL;
        int n     = nt * 16 + (lane & 15);
        int kbase = kt * 32 + (lane >> 4) * 8;
        unsigned short* o = bfr1 + (size_t)t * 8;
#pragma unroll
        for (int j = 0; j < 8; ++j) {
            int k = kbase + j;
            float w;
            if (seg == 0)      w = W1[k * LL1 + n] + W1[(384 + k) * LL1 + n];
            else if (seg == 1) w = W1[(128 + k) * LL1 + n] - W1[(384 + k) * LL1 + n];
            else               w = W1[(256 + k) * LL1 + n];
            unsigned short hb = f2bf(w);
            o[j] = (hl == 0) ? hb : f2bf(w - bf2f(hb));
        }
    } else {
        int t = (blk - 30) * 256 + threadIdx.x;
        if (t >= 18 * 64) return;
        int lane = t & 63;
        int fid  = t >> 6;
        int hl   = fid & 1;
        int nt   = (fid >> 1) % 3;
        int kt   = fid / 6;
        int n  = nt * 16 + (lane & 15);
        int kb = kt * 32 + (lane >> 4) * 8;
        unsigned short* o = bfr2 + (size_t)t * 8;
#pragma unroll
        for (int j = 0; j < 8; ++j) {
            int k = kb + j;
            float w = (k < LL1 && n < LL2) ? W2[k * LL2 + n] : 0.f;
            unsigned short hb = f2bf(w);
            o[j] = (hl == 0) ? hb : f2bf(w - bf2f(hb));
        }
    }
}

// ---------------------------------------------------------------------------
// Fully fused pipeline: one block per batch column b. The 200 s-rows
// p = s*1024 + b form a closed system for dice-stats (dim 0) and softmax (s),
// so GEMM1 -> stats -> dice -> GEMM2 -> stats -> dice -> W3 -> softmax ->
// out = w*facts never leave the CU. z1 (stride 81), the B1 staging buffer
// (61 KB) and z2 (stride 41) time-share one 67 KB LDS region.
__global__ __launch_bounds__(256, 2) void k_fused(
    const float* __restrict__ query, const float* __restrict__ facts,
    const unsigned short* __restrict__ bfr1, const unsigned short* __restrict__ bfr2,
    const float* __restrict__ b1, const float* __restrict__ a1,
    const float* __restrict__ b2, const float* __restrict__ a2,
    const float* __restrict__ W3, const float* __restrict__ b3,
    const void* __restrict__ mask, const int* __restrict__ flag,
    float* __restrict__ out) {
    const int tid  = threadIdx.x;
    const int w    = tid >> 6;
    const int lane = tid & 63;
    const int m    = lane & 15;
    const int quad = lane >> 4;
    const int b    = blockIdx.x;

    __shared__ __align__(16) float z1f[NTILE * 16 * 81 + 16];  // 16864 f = 67.4 KB
    __shared__ float psum[240], pssq[240];
    __shared__ float smean[LL1], sistd[LL1];
    __shared__ float sw3[LL2];
    __shared__ float red[4];
    __shared__ float wgt[SS];

    // wave w owns tiles {w, w+4, w+8, w+12} (tile 13..15 dead)
    int tile[4], pr[4], qr[4];
    bool tl[4];
#pragma unroll
    for (int t = 0; t < 4; ++t) {
        tile[t] = t * 4 + w;
        tl[t]   = (tile[t] < NTILE);
        int s = tile[t] * 16 + m;
        if (s > SS - 1) s = SS - 1;          // clamp pad rows (values unused)
        pr[t] = s * BB + b;
        qr[t] = pr[t] / SS;                  // faithful torch-tile permutation
    }

    // ---------------- GEMM1: z1 = [q|f|q*f] @ foldedW1 ----------------
    f32x4 acc[4][5];
#pragma unroll
    for (int t = 0; t < 4; ++t)
#pragma unroll
        for (int nt = 0; nt < 5; ++nt) acc[t][nt] = (f32x4){0.f, 0.f, 0.f, 0.f};

#pragma unroll 1
    for (int h = 0; h < 2; ++h) {
        if (h) __syncthreads();              // phase-0 LDS reads done
        {
            const int4* src = (const int4*)bfr1 + h * 3840 + tid;
            int4* dst = (int4*)z1f;
#pragma unroll
            for (int it = 0; it < 15; ++it)
                dst[it * 256 + tid] = src[it * 256];
        }
        __syncthreads();
        const unsigned short* lbuf = (const unsigned short*)z1f;
#pragma unroll
        for (int ktL = 0; ktL < 2; ++ktL) {
            const int dbase = (h * 2 + ktL) * 32 + quad * 8;
#pragma unroll
            for (int tp = 0; tp < 2; ++tp) {         // tile pairs keep VGPR lean
                float q8[2][8], f8[2][8];
#pragma unroll
                for (int u = 0; u < 2; ++u) {
                    const int t = tp * 2 + u;
                    const float* qp = query + (size_t)qr[t] * DD + dbase;
                    const float* fp = facts + (size_t)pr[t] * DD + dbase;
                    *(float4*)&q8[u][0] = *(const float4*)qp;
                    *(float4*)&q8[u][4] = *(const float4*)(qp + 4);
                    *(float4*)&f8[u][0] = *(const float4*)fp;
                    *(float4*)&f8[u][4] = *(const float4*)(fp + 4);
                }
#pragma unroll
                for (int seg = 0; seg < 3; ++seg) {
                    const int step = ktL * 3 + seg;
                    bf16x8 Bh[5], Bl[5];
#pragma unroll
                    for (int nt = 0; nt < 5; ++nt) {
                        Bh[nt] = *(const bf16x8*)&lbuf[((step * 2 + 0) * 5 + nt) * 512 + lane * 8];
                        Bl[nt] = *(const bf16x8*)&lbuf[((step * 2 + 1) * 5 + nt) * 512 + lane * 8];
                    }
#pragma unroll
                    for (int u = 0; u < 2; ++u) {
                        const int t = tp * 2 + u;
                        if (!tl[t]) continue;
                        float x8[8];
#pragma unroll
                        for (int j = 0; j < 8; ++j)
                            x8[j] = (seg == 0) ? q8[u][j]
                                  : (seg == 1 ? f8[u][j] : q8[u][j] * f8[u][j]);
                        bf16x8 ah, al;
                        split8(x8, ah, al);
#pragma unroll
                        for (int nt = 0; nt < 5; ++nt) {
                            acc[t][nt] = __builtin_amdgcn_mfma_f32_16x16x32_bf16(ah, Bh[nt], acc[t][nt], 0, 0, 0);
                            acc[t][nt] = __builtin_amdgcn_mfma_f32_16x16x32_bf16(al, Bh[nt], acc[t][nt], 0, 0, 0);
                            acc[t][nt] = __builtin_amdgcn_mfma_f32_16x16x32_bf16(ah, Bl[nt], acc[t][nt], 0, 0, 0);
                        }
                    }
                }
            }
        }
    }

    __syncthreads();                         // B1 staging dead -> reuse as z1
    {
        float b1v[5];
#pragma unroll
        for (int nt = 0; nt < 5; ++nt) b1v[nt] = b1[nt * 16 + m];
#pragma unroll
        for (int t = 0; t < 4; ++t) {
            if (!tl[t]) continue;
#pragma unroll
            for (int nt = 0; nt < 5; ++nt)
#pragma unroll
                for (int r = 0; r < 4; ++r)
                    z1f[(tile[t] * 16 + quad * 4 + r) * 81 + nt * 16 + m] = acc[t][nt][r] + b1v[nt];
        }
    }
    __syncthreads();

    // ---------------- stats1 over s (per l), 3 chunks x 80 cols ----------------
    if (tid < 240) {
        const int l = tid % LL1, c = tid / LL1;
        const int s0 = c * 67, s1 = (c == 2) ? SS : s0 + 67;
        float sum = 0.f, ssq = 0.f;
        for (int s = s0; s < s1; ++s) {
            float v = z1f[s * 81 + l];
            sum += v;
            ssq = fmaf(v, v, ssq);
        }
        psum[c * LL1 + l] = sum;
        pssq[c * LL1 + l] = ssq;
    }
    __syncthreads();
    if (tid < LL1) {
        float sum = psum[tid] + psum[LL1 + tid] + psum[2 * LL1 + tid];
        float ssq = pssq[tid] + pssq[LL1 + tid] + pssq[2 * LL1 + tid];
        float mn  = sum * (1.f / SS);
        float var = (ssq - (float)SS * mn * mn) * (1.f / (SS - 1));
        smean[tid] = mn;
        sistd[tid] = rsqrtf(var);
    }
    __syncthreads();

    // ---------------- GEMM2: dice1-on-load, K 80->96, N 40->48 ----------------
    const float alpha1 = *a1;
    f32x4 acc2[4][3];
#pragma unroll
    for (int t = 0; t < 4; ++t)
#pragma unroll
        for (int nt = 0; nt < 3; ++nt) acc2[t][nt] = (f32x4){0.f, 0.f, 0.f, 0.f};

#pragma unroll
    for (int kt = 0; kt < 3; ++kt) {
        bf16x8 Bh[3], Bl[3];
#pragma unroll
        for (int nt = 0; nt < 3; ++nt) {     // 18 KB, L2-hot, read direct
            Bh[nt] = *(const bf16x8*)(bfr2 + (size_t)((kt * 3 + nt) * 2 + 0) * 512 + lane * 8);
            Bl[nt] = *(const bf16x8*)(bfr2 + (size_t)((kt * 3 + nt) * 2 + 1) * 512 + lane * 8);
        }
        const int kb = kt * 32 + quad * 8;
        const bool lv = (kt < 2 || quad < 2);   // k < 80
#pragma unroll
        for (int t = 0; t < 4; ++t) {
            if (!tl[t]) continue;
            float x8[8];
            if (lv) {
                const float* zr = &z1f[(tile[t] * 16 + m) * 81 + kb];
#pragma unroll
                for (int j = 0; j < 8; ++j) {
                    float v  = zr[j];
                    float pp = 1.f / (1.f + expf(-(v - smean[kb + j]) * sistd[kb + j]));
                    x8[j] = v * (alpha1 + (1.f - alpha1) * pp);
                }
            } else {
#pragma unroll
                for (int j = 0; j < 8; ++j) x8[j] = 0.f;
            }
            bf16x8 ah, al;
            split8(x8, ah, al);
#pragma unroll
            for (int nt = 0; nt < 3; ++nt) {
                acc2[t][nt] = __builtin_amdgcn_mfma_f32_16x16x32_bf16(ah, Bh[nt], acc2[t][nt], 0, 0, 0);
                acc2[t][nt] = __builtin_amdgcn_mfma_f32_16x16x32_bf16(al, Bh[nt], acc2[t][nt], 0, 0, 0);
                acc2[t][nt] = __builtin_amdgcn_mfma_f32_16x16x32_bf16(ah, Bl[nt], acc2[t][nt], 0, 0, 0);
            }
        }
    }
    __syncthreads();                         // all z1 reads done -> reuse as z2

    {
        float b2v[3];
#pragma unroll
        for (int nt = 0; nt < 3; ++nt) {
            const int n = nt * 16 + m;
            b2v[nt] = (n < LL2) ? b2[n] : 0.f;
        }
#pragma unroll
        for (int t = 0; t < 4; ++t) {
            if (!tl[t]) continue;
#pragma unroll
            for (int r = 0; r < 4; ++r) {
                const int srow = tile[t] * 16 + quad * 4 + r;
                if (srow >= SS) continue;
#pragma unroll
                for (int nt = 0; nt < 3; ++nt) {
                    const int n = nt * 16 + m;
                    if (n < LL2) z1f[srow * 41 + n] = acc2[t][nt][r] + b2v[nt];
                }
            }
        }
    }
    __syncthreads();

    // ---------------- stats2, 6 chunks x 40 cols ----------------
    if (tid < 240) {
        const int l = tid % LL2, c = tid / LL2;
        const int s0 = c * 34, s1 = (c == 5) ? SS : s0 + 34;
        float sum = 0.f, ssq = 0.f;
        for (int s = s0; s < s1; ++s) {
            float v = z1f[s * 41 + l];
            sum += v;
            ssq = fmaf(v, v, ssq);
        }
        psum[c * LL2 + l] = sum;
        pssq[c * LL2 + l] = ssq;
    }
    __syncthreads();
    if (tid < LL2) {
        float sum = 0.f, ssq = 0.f;
#pragma unroll
        for (int c = 0; c < 6; ++c) {
            sum += psum[c * LL2 + tid];
            ssq += pssq[c * LL2 + tid];
        }
        float mn  = sum * (1.f / SS);
        float var = (ssq - (float)SS * mn * mn) * (1.f / (SS - 1));
        smean[tid] = mn;
        sistd[tid] = rsqrtf(var);
        sw3[tid]   = W3[tid];
    }
    __syncthreads();

    // ---------------- dice2 + W3 dot + masked softmax over s ----------------
    const float alpha2 = *a2;
    const int boolLayout = *flag;
    float logit = -3.0e38f;
    if (tid < SS) {
        float dot = b3[0];
#pragma unroll
        for (int k = 0; k < LL2; ++k) {
            float v  = z1f[tid * 41 + k];
            float pp = 1.f / (1.f + expf(-(v - smean[k]) * sistd[k]));
            float hh = v * (pp + alpha2 * (1.f - pp));
            dot = fmaf(hh, sw3[k], dot);
        }
        const int mi = tid * BB + b;
        const bool mk = boolLayout ? (((const unsigned char*)mask)[mi] != 0)
                                   : (((const int*)mask)[mi] != 0);
        logit = mk ? dot : MASK_FILL_F;
    }
    float v = logit;
#pragma unroll
    for (int off = 1; off < 64; off <<= 1) v = fmaxf(v, __shfl_xor(v, off, 64));
    if ((tid & 63) == 0) red[tid >> 6] = v;
    __syncthreads();
    const float smax = fmaxf(fmaxf(red[0], red[1]), fmaxf(red[2], red[3]));
    __syncthreads();
    const float e = (tid < SS) ? expf(logit - smax) : 0.f;
    v = e;
#pragma unroll
    for (int off = 1; off < 64; off <<= 1) v += __shfl_xor(v, off, 64);
    if ((tid & 63) == 0) red[tid >> 6] = v;
    __syncthreads();
    const float inv = 1.f / (red[0] + red[1] + red[2] + red[3]);
    if (tid < SS) wgt[tid] = e * inv;
    __syncthreads();

    // ---------------- epilogue: out[s][b][:] = wgt[s] * facts[s][b][:] ----------------
    const float4* f4 = (const float4*)facts;
    float4* o4 = (float4*)out;
#pragma unroll 5
    for (int i = tid; i < SS * 32; i += 256) {
        const int s  = i >> 5;
        const int d4 = i & 31;
        const size_t idx = (size_t)(s * BB + b) * 32 + d4;
        float4 f = f4[idx];
        const float ww = wgt[s];
        float4 o;
        o.x = f.x * ww; o.y = f.y * ww; o.z = f.z * ww; o.w = f.w * ww;
        o4[idx] = o;
    }
}

// ---------------------------------------------------------------------------
extern "C" void kernel_launch(void* const* d_in, const int* in_sizes, int n_in,
                              void* d_out, int out_size, void* d_ws, size_t ws_size,
                              hipStream_t stream) {
    const float* query = (const float*)d_in[0];
    const float* facts = (const float*)d_in[1];
    const void*  mask  = d_in[2];
    const float* W1 = (const float*)d_in[3];
    const float* b1 = (const float*)d_in[4];
    const float* a1 = (const float*)d_in[5];
    const float* W2 = (const float*)d_in[6];
    const float* b2 = (const float*)d_in[7];
    const float* a2 = (const float*)d_in[8];
    const float* W3 = (const float*)d_in[9];
    const float* b3 = (const float*)d_in[10];

    // workspace: bfr1 122880 B @0 ; bfr2 18432 B @128K ; flag @160K
    unsigned short* bfr1 = (unsigned short*)d_ws;
    unsigned short* bfr2 = (unsigned short*)((char*)d_ws + 131072);
    int* flag = (int*)((char*)d_ws + 163840);

    k_prep_all<<<36, 256, 0, stream>>>(W1, W2, (const unsigned char*)mask, bfr1, bfr2, flag);
    k_fused<<<BB, 256, 0, stream>>>(query, facts, bfr1, bfr2, b1, a1, b2, a2,
                                    W3, b3, mask, flag, (float*)d_out);
}